// Round 12
// baseline (675.966 us; speedup 1.0000x reference)
//
#include <hip/hip_runtime.h>

#define CH  128   // C: node feature channels
#define HID 128   // H: hidden channels
#define EAD 8     // edge_attr dim

typedef __attribute__((ext_vector_type(8))) short short8v;   // 8 bf16 (4 VGPRs)
typedef __attribute__((ext_vector_type(4))) float floatx4;   // MFMA acc

// ---------------- helpers ----------------
__device__ __forceinline__ void load8(const float* __restrict__ p, float* r) {
    float4 v0 = *(const float4*)p;
    float4 v1 = *(const float4*)(p + 4);
    r[0]=v0.x; r[1]=v0.y; r[2]=v0.z; r[3]=v0.w;
    r[4]=v1.x; r[5]=v1.y; r[6]=v1.z; r[7]=v1.w;
}
__device__ __forceinline__ void store8(float* p, const float* v) {
    *(float4*)p       = make_float4(v[0], v[1], v[2], v[3]);
    *(float4*)(p + 4) = make_float4(v[4], v[5], v[6], v[7]);
}
__device__ __forceinline__ void zero88(float a[8][8]) {
#pragma unroll
    for (int i = 0; i < 8; i++)
#pragma unroll
        for (int j = 0; j < 8; j++) a[i][j] = 0.f;
}
__device__ __forceinline__ unsigned short f2bf(float f) {   // RNE float->bf16 bits
    union { float f; unsigned u; } v; v.f = f;
    return (unsigned short)((v.u + 0x7FFFu + ((v.u >> 16) & 1u)) >> 16);
}
__device__ __forceinline__ float bf2f(unsigned short h) {
    union { unsigned u; float f; } v; v.u = ((unsigned)h) << 16;
    return v.f;
}

// 64-row x 128-col GEMM accumulate, 8x8 register tile, 128 threads (fp32 FMA).
template <int K>
__device__ __forceinline__ void gemm_tile8(const float* sA, int strideA,
                                           const float* __restrict__ B, int ldb,
                                           int tr8, int jb, float acc[8][8]) {
#pragma unroll 2
    for (int k = 0; k < K; k += 4) {
        float av[8][4];
#pragma unroll
        for (int i = 0; i < 8; i++) {
            float4 t = *(const float4*)(sA + (tr8 + 8 * i) * strideA + k);
            av[i][0] = t.x; av[i][1] = t.y; av[i][2] = t.z; av[i][3] = t.w;
        }
#pragma unroll
        for (int kk = 0; kk < 4; kk++) {
            float b8[8];
            load8(B + (size_t)(k + kk) * ldb + jb, b8);
#pragma unroll
            for (int i = 0; i < 8; i++)
#pragma unroll
                for (int j = 0; j < 8; j++)
                    acc[i][j] = fmaf(av[i][kk], b8[j], acc[i][j]);
        }
    }
}

// ---------------- kernel 1: per-node factored edge-MLP1 partials ----------------
__global__ __launch_bounds__(128, 2)
void precompute_kernel(const float* __restrict__ x, const float* __restrict__ w1,
                       const float* __restrict__ b1, float* __restrict__ tbl, int N) {
    __shared__ float sX[64 * 132];
    const int tid = threadIdx.x;
    const int n0  = blockIdx.x * 64;
    // linear coalesced copy of the dense 64x128 x-tile (consecutive lanes ->
    // consecutive float4s; was scattered 16B reads at stride 512B)
#pragma unroll
    for (int t = 0; t < 16; t++) {
        const int idx = t * 128 + tid;               // 0..2047
        const int n = idx >> 5, cc = (idx & 31) * 4;
        int gn = n0 + n; if (gn >= N) gn = N - 1;
        *(float4*)(sX + n * 132 + cc) = *(const float4*)(x + (size_t)gn * CH + cc);
    }
    __syncthreads();
    const int tr8 = tid & 7, jb = (tid >> 3) * 8;
    float acc[8][8];

    zero88(acc);
    gemm_tile8<128>(sX, 132, w1, HID, tr8, jb, acc);          // rows 0..127 of w_e1
    float bb[8]; load8(b1 + jb, bb);
#pragma unroll
    for (int i = 0; i < 8; i++) {
        const int gn = n0 + tr8 + 8 * i;
        if (gn < N) {
            float v[8];
#pragma unroll
            for (int j = 0; j < 8; j++) v[j] = acc[i][j] + bb[j];
            store8(tbl + (size_t)gn * 256 + jb, v);
        }
    }

    zero88(acc);
    gemm_tile8<128>(sX, 132, w1 + CH * HID, HID, tr8, jb, acc); // rows 128..255
#pragma unroll
    for (int i = 0; i < 8; i++) {
        const int gn = n0 + tr8 + 8 * i;
        if (gn < N) store8(tbl + (size_t)gn * 256 + 128 + jb, acc[i]);
    }
}

// ---------------- CSR build: histogram -> scan -> scatter ----------------
__global__ void hist_kernel(const int* __restrict__ ei, int* __restrict__ deg, int E) {
    const int e = blockIdx.x * blockDim.x + threadIdx.x;
    if (e < E) atomicAdd(&deg[ei[e]], 1);
}

__global__ void scan_kernel(const int* __restrict__ deg, int* __restrict__ row_ptr,
                            int* __restrict__ cursor, int N) {
    __shared__ int part[1024];
    const int tid = threadIdx.x;
    const int chunk = (N + 1023) / 1024;
    const int lo = tid * chunk;
    const int hi = (lo + chunk < N) ? lo + chunk : N;
    int s = 0;
    for (int i = lo; i < hi; i++) s += deg[i];
    part[tid] = s;
    __syncthreads();
    for (int off = 1; off < 1024; off <<= 1) {   // Hillis-Steele inclusive scan
        int v = (tid >= off) ? part[tid - off] : 0;
        __syncthreads();
        part[tid] += v;
        __syncthreads();
    }
    int run = (tid == 0) ? 0 : part[tid - 1];    // exclusive base
    for (int i = lo; i < hi; i++) {
        row_ptr[i] = run; cursor[i] = run;
        run += deg[i];
    }
    if (tid == 1023) row_ptr[N] = run;           // total = E
}

__global__ void scatter_kernel(const int* __restrict__ ei, int* cursor,
                               int* __restrict__ perm, int E) {
    const int e = blockIdx.x * blockDim.x + threadIdx.x;
    if (e < E) {
        const int p = atomicAdd(&cursor[ei[e]], 1);
        perm[p] = e;
    }
}

// ---------------- prep: w2 (f32, [k][n]) -> w2t (bf16, [n][k] transposed) --------
__global__ void prep_w2t(const float* __restrict__ w2, unsigned short* __restrict__ w2t) {
    const int idx = blockIdx.x * 256 + threadIdx.x;   // 16384 total
    const int n = idx >> 7, k = idx & 127;
    w2t[idx] = f2bf(w2[k * HID + n]);
}

// ---------------- kernel 2: edge model, MFMA MLP2 + segmented reduce ----------
// Staging: 4 lanes/edge, CHUNK-CONSECUTIVE (lanes 4s..4s+3 read adjacent 16B
// chunks -> every random 64B line fully utilized; was 16B-per-line = 4x waste).
// MLP2: mfma_f32_16x16x32_bf16, C/D layout (m89/m91) col=lane&15, row=(lane>>4)*4+reg.
__global__ __launch_bounds__(128, 2)
void edge_kernel_sorted(const float* __restrict__ tbl, const float* __restrict__ coord,
                        const int* __restrict__ ei, const float* __restrict__ ea,
                        const float* __restrict__ w1,
                        const unsigned short* __restrict__ w2t,
                        const float* __restrict__ b2, const int* __restrict__ perm,
                        const int* __restrict__ row_ptr, float* agg, int E) {
    __shared__ __align__(16) unsigned short sHu[64 * 136];  // h1/feat tile, bf16
    __shared__ float sW[9 * 128];   // w_e1 rows 256..264 (radial + edge_attr), f32
    __shared__ int   sRow[64];      // sorted row id per tile slot
    const int tid = threadIdx.x;

    // bijective XCD swizzle (m204)
    const int nwg = gridDim.x;
    const int qq = nwg >> 3, rr = nwg & 7;
    const int xcd = blockIdx.x & 7, idx = blockIdx.x >> 3;
    const int wg  = (xcd < rr) ? (xcd * (qq + 1) + idx)
                               : (rr * (qq + 1) + (xcd - rr) * qq + idx);
    const int e0  = wg * 64;           // E % 64 == 0: no tail

    for (int i = tid; i < 9 * 128; i += 128) sW[i] = w1[256 * HID + i];
    __syncthreads();

    // ---- stage h1 tile (bf16): 4 lanes/edge x 2 passes, chunk-consecutive ----
#pragma unroll
    for (int pass = 0; pass < 2; pass++) {
        const int s = pass * 32 + (tid >> 2);  // edge slot 0..63
        const int q = tid & 3;                 // 16B-chunk phase
        const int pe = perm[e0 + s];           // original edge id
        const int r = ei[pe];
        const int c = ei[E + pe];
        if (q == 0) sRow[s] = r;
        const float dx = coord[3 * r + 0] - coord[3 * c + 0];
        const float dy = coord[3 * r + 1] - coord[3 * c + 1];
        const float dz = coord[3 * r + 2] - coord[3 * c + 2];
        const float radial = fmaf(dx, dx, fmaf(dy, dy, dz * dz));
        float eav[8];
        load8(ea + (size_t)pe * EAD, eav);
        const float* tr = tbl + (size_t)r * 256;         // row partial (+b_e1)
        const float* tc = tbl + (size_t)c * 256 + 128;   // col partial
        unsigned short* drow = sHu + s * 136;
#pragma unroll
        for (int u = 0; u < 8; u++) {
            const int ch = u * 16 + q * 4;     // lanes 4s..4s+3 -> 64B contiguous
            float4 a  = *(const float4*)(tr + ch);
            float4 b  = *(const float4*)(tc + ch);
            float4 wv = *(const float4*)(sW + ch);       // radial row (broadcast)
            float v0 = a.x + b.x + radial * wv.x;
            float v1 = a.y + b.y + radial * wv.y;
            float v2 = a.z + b.z + radial * wv.z;
            float v3 = a.w + b.w + radial * wv.w;
#pragma unroll
            for (int m = 0; m < 8; m++) {
                float4 we = *(const float4*)(sW + (1 + m) * 128 + ch);  // broadcast
                v0 = fmaf(eav[m], we.x, v0);
                v1 = fmaf(eav[m], we.y, v1);
                v2 = fmaf(eav[m], we.z, v2);
                v3 = fmaf(eav[m], we.w, v3);
            }
            const unsigned lo = (unsigned)f2bf(fmaxf(v0, 0.f))
                              | ((unsigned)f2bf(fmaxf(v1, 0.f)) << 16);
            const unsigned hi = (unsigned)f2bf(fmaxf(v2, 0.f))
                              | ((unsigned)f2bf(fmaxf(v3, 0.f)) << 16);
            *(uint2*)(drow + ch) = make_uint2(lo, hi);
        }
    }
    __syncthreads();

    // ---- MLP2 via MFMA ----
    const int lane = tid & 63;
    const int wcol = (tid >> 6) * 64;      // wave 0: cols 0..63, wave 1: 64..127
    const int lr = lane & 15;              // A-row / B-col / C-col within tile
    const int lg = lane >> 4;              // k-group / C-row-group
    floatx4 acc[4][4];                     // [mt][ct]
#pragma unroll
    for (int mt = 0; mt < 4; mt++)
#pragma unroll
        for (int ct = 0; ct < 4; ct++)
#pragma unroll
            for (int j = 0; j < 4; j++) acc[mt][ct][j] = 0.f;

#pragma unroll
    for (int kc = 0; kc < 4; kc++) {
        short8v afr[4];                    // A[mt*16+lr][kc*32+lg*8 .. +8]
#pragma unroll
        for (int mt = 0; mt < 4; mt++)
            afr[mt] = *(const short8v*)(sHu + (mt * 16 + lr) * 136 + kc * 32 + lg * 8);
        short8v bfr[4];                    // B[kc*32+lg*8..][wcol+ct*16+lr] from w2t[n][k]
#pragma unroll
        for (int ct = 0; ct < 4; ct++)
            bfr[ct] = *(const short8v*)(w2t + (size_t)(wcol + ct * 16 + lr) * HID
                                            + kc * 32 + lg * 8);
#pragma unroll
        for (int mt = 0; mt < 4; mt++)
#pragma unroll
            for (int ct = 0; ct < 4; ct++)
                acc[mt][ct] = __builtin_amdgcn_mfma_f32_16x16x32_bf16(
                                  afr[mt], bfr[ct], acc[mt][ct], 0, 0, 0);
    }

    float b2v[4];
#pragma unroll
    for (int ct = 0; ct < 4; ct++) b2v[ct] = b2[wcol + ct * 16 + lr];
    __syncthreads();               // all A-fragment reads done before overwrite

    // ---- write relu(feat) back to LDS (bf16) ----
#pragma unroll
    for (int mt = 0; mt < 4; mt++)
#pragma unroll
        for (int ct = 0; ct < 4; ct++)
#pragma unroll
            for (int r_ = 0; r_ < 4; r_++) {
                const int row = mt * 16 + lg * 4 + r_;
                const int col = wcol + ct * 16 + lr;
                sHu[row * 136 + col] = f2bf(fmaxf(acc[mt][ct][r_] + b2v[ct], 0.f));
            }
    __syncthreads();

    // ---- segmented reduction: 2 passes of 32 slots, 4 threads (32ch) per slot ----
#pragma unroll
    for (int base = 0; base < 64; base += 32) {
        const int s = base + (tid >> 2), q4 = tid & 3;
        const int r = sRow[s];
        const bool head = (s == 0) || (sRow[s - 1] != r);
        if (head) {
            float sum[32];
            {
                const short8v* sp = (const short8v*)(sHu + s * 136 + q4 * 32);
#pragma unroll
                for (int v8 = 0; v8 < 4; v8++) {
                    short8v t = sp[v8];
#pragma unroll
                    for (int j = 0; j < 8; j++)
                        sum[v8 * 8 + j] = bf2f((unsigned short)t[j]);
                }
            }
            int L = 1;
            while (s + L < 64 && sRow[s + L] == r) {
                const short8v* sp = (const short8v*)(sHu + (s + L) * 136 + q4 * 32);
#pragma unroll
                for (int v8 = 0; v8 < 4; v8++) {
                    short8v t = sp[v8];
#pragma unroll
                    for (int j = 0; j < 8; j++)
                        sum[v8 * 8 + j] += bf2f((unsigned short)t[j]);
                }
                L++;
            }
            float* dst = agg + (size_t)r * HID + q4 * 32;
            const bool interior = (row_ptr[r] >= e0) && (row_ptr[r + 1] <= e0 + 64);
            if (interior) {     // this tile holds ALL edges of row r -> plain store
#pragma unroll
                for (int j = 0; j < 32; j += 4)
                    *(float4*)(dst + j) = make_float4(sum[j], sum[j+1], sum[j+2], sum[j+3]);
            } else {            // row spans tiles -> atomic (rare: ~2 rows/tile)
#pragma unroll
                for (int j = 0; j < 32; j++) atomicAdd(dst + j, sum[j]);
            }
        }
    }
}

// ---------------- kernel 3: node model ----------------
__global__ __launch_bounds__(128, 2)
void node_kernel(const float* __restrict__ x, const float* agg,
                 const float* __restrict__ w1, const float* __restrict__ b1,
                 const float* __restrict__ w2, const float* __restrict__ b2,
                 float* out, int N) {
    __shared__ float sA[64 * 260];
    const int tid = threadIdx.x;
    const int n0  = blockIdx.x * 64;
    // linear coalesced copies of the dense x-tile and agg-tile
#pragma unroll
    for (int t = 0; t < 16; t++) {
        const int idx = t * 128 + tid;               // 0..2047
        const int n = idx >> 5, cc = (idx & 31) * 4;
        int gn = n0 + n; if (gn >= N) gn = N - 1;
        *(float4*)(sA + n * 260 + cc)      = *(const float4*)(x   + (size_t)gn * CH  + cc);
        *(float4*)(sA + n * 260 + CH + cc) = *(const float4*)(agg + (size_t)gn * HID + cc);
    }
    __syncthreads();
    const int tr8 = tid & 7, jb = (tid >> 3) * 8;
    float acc[8][8];
    zero88(acc);
    gemm_tile8<256>(sA, 260, w1, HID, tr8, jb, acc);
    float bb[8]; load8(b1 + jb, bb);
    float h[8][8];
#pragma unroll
    for (int i = 0; i < 8; i++)
#pragma unroll
        for (int j = 0; j < 8; j++) h[i][j] = fmaxf(acc[i][j] + bb[j], 0.f);
    __syncthreads();   // all MLP1 reads of sA complete
#pragma unroll
    for (int i = 0; i < 8; i++) store8(sA + (tr8 + 8 * i) * 260 + jb, h[i]);
    __syncthreads();
    zero88(acc);
    gemm_tile8<128>(sA, 260, w2, CH, tr8, jb, acc);
    float b2v[8]; load8(b2 + jb, b2v);
#pragma unroll
    for (int i = 0; i < 8; i++) {
        const int gn = n0 + tr8 + 8 * i;
        if (gn < N) {
            float v[8];
#pragma unroll
            for (int j = 0; j < 8; j++) v[j] = acc[i][j] + b2v[j];
            store8(out + (size_t)gn * CH + jb, v);
        }
    }
}

// ---------------- launch ----------------
extern "C" void kernel_launch(void* const* d_in, const int* in_sizes, int n_in,
                              void* d_out, int out_size, void* d_ws, size_t ws_size,
                              hipStream_t stream) {
    const float* x     = (const float*)d_in[0];
    const float* coord = (const float*)d_in[1];
    const int*   ei    = (const int*)d_in[2];   // [2,E]: row = ei[0:E], col = ei[E:2E]
    const float* ea    = (const float*)d_in[3];
    const float* w_e1  = (const float*)d_in[4];
    const float* b_e1  = (const float*)d_in[5];
    const float* w_e2  = (const float*)d_in[6];
    const float* b_e2  = (const float*)d_in[7];
    const float* w_n1  = (const float*)d_in[8];
    const float* b_n1  = (const float*)d_in[9];
    const float* w_n2  = (const float*)d_in[10];
    const float* b_n2  = (const float*)d_in[11];

    const int N = in_sizes[0] / CH;
    const int E = in_sizes[2] / 2;

    float* out = (float*)d_out;
    float* agg = out;                 // agg lives in d_out, aliased

    // workspace carve (all 16B-aligned): tbl | perm | w2t | deg | row_ptr | cursor
    char* w = (char*)d_ws;
    float* tbl   = (float*)w;          w += (size_t)N * 256 * sizeof(float);  // 51.2 MB
    int* perm    = (int*)w;            w += (size_t)E * sizeof(int);          // 2.4 MB
    unsigned short* w2t = (unsigned short*)w;  w += (size_t)HID * HID * 2;    // 32 KB
    int* deg     = (int*)w;            w += (size_t)N * sizeof(int);
    int* row_ptr = (int*)w;            w += (size_t)(N + 1) * sizeof(int);
    int* cursor  = (int*)w;

    hipMemsetAsync(agg, 0, (size_t)N * HID * sizeof(float), stream);
    hipMemsetAsync(deg, 0, (size_t)N * sizeof(int), stream);

    precompute_kernel<<<dim3((N + 63) / 64), dim3(128), 0, stream>>>(x, w_e1, b_e1, tbl, N);
    prep_w2t<<<dim3(HID * HID / 256), dim3(256), 0, stream>>>(w_e2, w2t);
    hist_kernel<<<dim3((E + 255) / 256), dim3(256), 0, stream>>>(ei, deg, E);
    scan_kernel<<<dim3(1), dim3(1024), 0, stream>>>(deg, row_ptr, cursor, N);
    scatter_kernel<<<dim3((E + 255) / 256), dim3(256), 0, stream>>>(ei, cursor, perm, E);
    edge_kernel_sorted<<<dim3(E / 64), dim3(128), 0, stream>>>(tbl, coord, ei, ea,
                                                               w_e1, w2t, b_e2,
                                                               perm, row_ptr, agg, E);
    node_kernel<<<dim3((N + 63) / 64), dim3(128), 0, stream>>>(x, agg, w_n1, b_n1,
                                                               w_n2, b_n2, out, N);
}